// Round 8
// baseline (138.826 us; speedup 1.0000x reference)
//
#include <hip/hip_runtime.h>

#define BB 128
#define LL 336
#define CC 862
#define PRED 96
#define WIN 12
#define S_IN 28
#define S_OUT 8
#define CT 32
#define NTILES ((CC + CT - 1) / CT)   // 27

#define SQRT12F 3.4641016151377544f

// -Sb(t)/sqrt(12), Sb(t) = 2*sum_{k=1..5} sin(pi*k*t/6)   (exact closed forms)
__device__ const float COEFP[12] = {
    0.0f, -2.1547005383792515f, 0.0f, -0.5773502691896258f,
    0.0f, -0.15470053837925146f, 0.0f, 0.15470053837925146f,
    0.0f,  0.5773502691896258f, 0.0f,  2.1547005383792515f
};

// ---- prep kernels ----

// wXT layout: [p][s][c]  (c contiguous -> coalesced per-lane weight reads)
__global__ void prep_wT(const float* __restrict__ wA, const float* __restrict__ wP,
                        float* __restrict__ wAT, float* __restrict__ wPT) {
    int i = blockIdx.x * 256 + threadIdx.x;          // i = (p*S_IN + s)*CC + c
    if (i >= S_OUT * S_IN * CC) return;
    int c  = i % CC;
    int ps = i / CC;
    int s  = ps % S_IN;
    int p  = ps / S_IN;
    int src = (c * S_OUT + p) * S_IN + s;
    wAT[i] = wA[src];
    wPT[i] = wP[src];
}

__global__ void prep_mcoef(const float* __restrict__ wA, float* __restrict__ mcoefT) {
    int i = blockIdx.x * 256 + threadIdx.x;          // [p][c]
    if (i >= S_OUT * CC) return;
    int c = i % CC;
    int p = i / CC;
    float s = 0.f;
    for (int k = 0; k < S_IN; ++k) s += wA[(c * S_OUT + p) * S_IN + k];
    mcoefT[i] = 1.0f - s;
}

__global__ void prep_bias(const float* __restrict__ bA, const float* __restrict__ bP,
                          float* __restrict__ biasv) {
    int i = blockIdx.x * 256 + threadIdx.x;          // [t][p][c]
    if (i >= 12 * S_OUT * CC) return;
    int c = i % CC;
    int tp = i / CC;
    int p = tp % S_OUT;
    int t = tp / S_OUT;
    float v = COEFP[t] * bP[c * S_OUT + p];
    if (t == 0) v += SQRT12F * bA[c * S_OUT + p];
    biasv[i] = v;
}

// ---- fused main kernel: thread = (cc, p). x staged once in LDS;
//      weights read per-thread with ZERO block-level redundancy;
//      mean computed per-thread inside the s-loop (no sync). ----

template <bool TRANS>
__global__ __launch_bounds__(256) void fused8(
    const float* __restrict__ x,
    const float* __restrict__ wAT, const float* __restrict__ wPT,
    const float* __restrict__ mcoefT, const float* __restrict__ biasv,
    const float* __restrict__ wA_raw, const float* __restrict__ wP_raw,
    const float* __restrict__ bAr, const float* __restrict__ bPr,
    float* __restrict__ out)
{
    __shared__ float sx[LL][CT];      // 43008 B

    const int b   = blockIdx.y;
    const int c0  = blockIdx.x * CT;
    const int NC  = min(CT, CC - c0); // 32 or 30 (even)
    const int tid = threadIdx.x;

    // ---- stage x[b, :, c0:c0+NC] via float2 (21 independent loads/thread) ----
    {
        const int col2 = tid & 15;       // float2 slot in row
        const int r0   = tid >> 4;       // 0..15
        const int cc2  = 2 * col2;
        int csrc = cc2;
        if (csrc + 1 >= NC) csrc = NC - 2;      // clamp (NC even, >=2)
        const float* base = x + ((size_t)b * LL) * CC + c0 + csrc;
        #pragma unroll
        for (int r = r0; r < LL; r += 16) {
            float2 v = *reinterpret_cast<const float2*>(base + (size_t)r * CC);
            sx[r][cc2]     = v.x;
            sx[r][cc2 + 1] = v.y;
        }
    }
    __syncthreads();

    const int cc = tid & 31;
    const int p  = tid >> 5;             // 0..7, all active
    const int c  = c0 + cc;
    const bool wr = (cc < NC);
    const int cl = wr ? c : (CC - 1);    // clamped for global loads

    float A0 = 0.f, A6 = 0.f;
    float Au[5] = {0.f, 0.f, 0.f, 0.f, 0.f};
    float Pv[5] = {0.f, 0.f, 0.f, 0.f, 0.f};
    float msum = 0.f;
    float sw = 0.f;                      // fallback: sum of wA over s

    #pragma unroll
    for (int s = 0; s < S_IN; ++s) {
        float wa, wp;
        if (TRANS) {
            wa = wAT[(size_t)(p * S_IN + s) * CC + cl];
            wp = wPT[(size_t)(p * S_IN + s) * CC + cl];
        } else {
            wa = wA_raw[(size_t)(cl * S_OUT + p) * S_IN + s];
            wp = wP_raw[(size_t)(cl * S_OUT + p) * S_IN + s];
            sw += wa;
        }
        float x12[12];
        #pragma unroll
        for (int t = 0; t < 12; ++t) x12[t] = sx[s * WIN + t][cc];

        A0 = fmaf(wa, x12[0], A0);
        A6 = fmaf(wa, x12[6], A6);
        float usum = x12[0] + x12[6];
        #pragma unroll
        for (int t = 1; t <= 5; ++t) {
            const float uu = x12[t] + x12[12 - t];
            const float vv = x12[t] - x12[12 - t];
            Au[t - 1] = fmaf(wa, uu, Au[t - 1]);
            Pv[t - 1] = fmaf(wp, vv, Pv[t - 1]);
            usum += uu;
        }
        msum += usum;
    }

    if (!wr) return;

    const float mean = msum * (1.0f / LL);

    float mc, bias[12];
    if (TRANS) {
        mc = mcoefT[p * CC + c];
        #pragma unroll
        for (int t = 0; t < 12; ++t) bias[t] = biasv[(size_t)(t * S_OUT + p) * CC + c];
    } else {
        mc = 1.0f - sw;
        const float ba = bAr[c * S_OUT + p], bp = bPr[c * S_OUT + p];
        #pragma unroll
        for (int t = 0; t < 12; ++t) {
            bias[t] = COEFP[t] * bp + (t == 0 ? SQRT12F * ba : 0.f);
        }
    }

    const float mb = mean * mc;
    float* ob = out + ((size_t)b * PRED + p * WIN) * CC + c;

    ob[0]               = A0 + mb + bias[0];
    ob[(size_t)6 * CC]  = A6 + mb + bias[6];
    #pragma unroll
    for (int t = 1; t <= 5; ++t) {
        ob[(size_t)t * CC]        = 0.5f * (Au[t-1] + Pv[t-1]) + mb + bias[t];
        ob[(size_t)(12 - t) * CC] = 0.5f * (Au[t-1] - Pv[t-1]) + mb + bias[12 - t];
    }
}

extern "C" void kernel_launch(void* const* d_in, const int* in_sizes, int n_in,
                              void* d_out, int out_size, void* d_ws, size_t ws_size,
                              hipStream_t stream) {
    const float* x  = (const float*)d_in[0];
    const float* wA = (const float*)d_in[1];
    const float* bA = (const float*)d_in[2];
    const float* wP = (const float*)d_in[3];
    const float* bP = (const float*)d_in[4];
    float* out = (float*)d_out;

    const size_t nW  = (size_t)S_OUT * S_IN * CC;    // 193088
    const size_t nM  = (size_t)S_OUT * CC;           // 6896
    const size_t nBv = (size_t)12 * S_OUT * CC;      // 82752
    const size_t need = (2 * nW + nM + nBv) * sizeof(float);

    dim3 grid(NTILES, BB);

    if (ws_size >= need) {
        float* wAT    = (float*)d_ws;
        float* wPT    = wAT + nW;
        float* mcoefT = wPT + nW;
        float* biasv  = mcoefT + nM;

        prep_wT<<<(int)((nW + 255) / 256), 256, 0, stream>>>(wA, wP, wAT, wPT);
        prep_mcoef<<<(int)((nM + 255) / 256), 256, 0, stream>>>(wA, mcoefT);
        prep_bias<<<(int)((nBv + 255) / 256), 256, 0, stream>>>(bA, bP, biasv);

        fused8<true><<<grid, 256, 0, stream>>>(
            x, wAT, wPT, mcoefT, biasv,
            nullptr, nullptr, nullptr, nullptr, out);
    } else {
        fused8<false><<<grid, 256, 0, stream>>>(
            x, nullptr, nullptr, nullptr, nullptr,
            wA, wP, bA, bP, out);
    }
}

// Round 9
// 89.401 us; speedup vs baseline: 1.5528x; 1.5528x over previous
//
#include <hip/hip_runtime.h>

#define BB 128
#define LL 336
#define CC 862
#define PRED 96
#define WIN 12
#define S_IN 28
#define S_OUT 8
#define NQ 7                      // s chunks of 4
#define CT 32
#define NTILES ((CC + CT - 1) / CT)   // 27

#define SQRT12F 3.4641016151377544f

// -Sb(t)/sqrt(12), Sb(t) = 2*sum_{k=1..5} sin(pi*k*t/6)   (exact closed forms)
__device__ const float COEFP[12] = {
    0.0f, -2.1547005383792515f, 0.0f, -0.5773502691896258f,
    0.0f, -0.15470053837925146f, 0.0f, 0.15470053837925146f,
    0.0f,  0.5773502691896258f, 0.0f,  2.1547005383792515f
};

// ---- prep kernels ----

// repacked layout: wX4[((q*S_OUT + p)*CC + c)*4 + j]  = wX[c][p][4q+j]
__global__ void prep_w4(const float* __restrict__ wA, const float* __restrict__ wP,
                        float* __restrict__ wA4, float* __restrict__ wP4) {
    int i = blockIdx.x * 256 + threadIdx.x;
    if (i >= NQ * S_OUT * CC * 4) return;
    int j  = i & 3;
    int c  = (i >> 2) % CC;
    int p  = (i / (4 * CC)) % S_OUT;
    int q  = i / (4 * CC * S_OUT);
    int s  = 4 * q + j;
    int src = (c * S_OUT + p) * S_IN + s;
    wA4[i] = wA[src];
    wP4[i] = wP[src];
}

__global__ void prep_mcoef(const float* __restrict__ wA, float* __restrict__ mcoefT) {
    int i = blockIdx.x * 256 + threadIdx.x;          // [p][c]
    if (i >= S_OUT * CC) return;
    int c = i % CC;
    int p = i / CC;
    float s = 0.f;
    for (int k = 0; k < S_IN; ++k) s += wA[(c * S_OUT + p) * S_IN + k];
    mcoefT[i] = 1.0f - s;
}

__global__ void prep_bias(const float* __restrict__ bA, const float* __restrict__ bP,
                          float* __restrict__ biasv) {
    int i = blockIdx.x * 256 + threadIdx.x;          // [t][p][c]
    if (i >= 12 * S_OUT * CC) return;
    int c = i % CC;
    int tp = i / CC;
    int p = tp % S_OUT;
    int t = tp / S_OUT;
    float v = COEFP[t] * bP[c * S_OUT + p];
    if (t == 0) v += SQRT12F * bA[c * S_OUT + p];
    biasv[i] = v;
}

// ---- fused main kernel: r4 structure + 2-stage x prefetch pipeline ----
// thread = (cc 0..31, pair 0..7); pairs 0..6 active; t=pair, tr=(12-t)%12
// launch_bounds(256,4): VGPR cap 128 (r3: (256,8) spilled -> 2.6 GB scratch;
// r8: no cap + full unroll -> 228 VGPR -> 11% occupancy).

template <bool TRANS>
__global__ __launch_bounds__(256, 4) void fused9(
    const float* __restrict__ x,
    const float* __restrict__ wA4, const float* __restrict__ wP4,
    const float* __restrict__ mcoefT, const float* __restrict__ biasv,
    const float* __restrict__ wA_raw, const float* __restrict__ wP_raw,
    const float* __restrict__ bAr, const float* __restrict__ bPr,
    float* __restrict__ out)
{
    __shared__ float ssum[7][CT];    // 896 B

    const int b    = blockIdx.y;
    const int c0   = blockIdx.x * CT;
    const int NC   = min(CT, CC - c0);
    const int tid  = threadIdx.x;
    const int cc   = tid & 31;
    const int pair = tid >> 5;          // 0..7
    const int c    = c0 + cc;
    const int cl   = (c < CC) ? c : (CC - 1);   // clamped for loads
    const int t    = (pair < 7) ? pair : 0;
    const int tr   = (12 - t) % 12;
    const bool active = (pair < 7) && (cc < NC);

    float A[S_OUT], P[S_OUT];
    #pragma unroll
    for (int p = 0; p < S_OUT; ++p) { A[p] = 0.f; P[p] = 0.f; }
    float su = 0.f;

    const float* pt = x + ((size_t)b * LL + t)  * CC + cl;
    const float* pr = x + ((size_t)b * LL + tr) * CC + cl;

    // prologue: load q=0 x (8 independent loads)
    float cxt[4], cxr[4];
    #pragma unroll
    for (int j = 0; j < 4; ++j) {
        const size_t off = (size_t)(j * WIN) * CC;
        cxt[j] = pt[off];
        cxr[j] = pr[off];
    }

    #pragma unroll 1
    for (int q = 0; q < NQ; ++q) {
        // prefetch next iteration's x FIRST (independent of everything below)
        float nxt[4], nxr[4];
        if (q < NQ - 1) {
            #pragma unroll
            for (int j = 0; j < 4; ++j) {
                const size_t off = (size_t)(((q + 1) * 4 + j) * WIN) * CC;
                nxt[j] = pt[off];
                nxr[j] = pr[off];
            }
        }

        // compute u/v from the already-resident registers
        float u[4], v[4];
        #pragma unroll
        for (int j = 0; j < 4; ++j) {
            u[j] = cxt[j] + cxr[j];
            v[j] = cxt[j] - cxr[j];
        }
        su += (u[0] + u[1]) + (u[2] + u[3]);

        if (TRANS) {
            const float4* wa4 = reinterpret_cast<const float4*>(wA4) + (size_t)(q * S_OUT) * CC + cl;
            const float4* wp4 = reinterpret_cast<const float4*>(wP4) + (size_t)(q * S_OUT) * CC + cl;
            #pragma unroll
            for (int p = 0; p < S_OUT; ++p) {
                float4 wa = wa4[(size_t)p * CC];
                float4 wp = wp4[(size_t)p * CC];
                A[p] = fmaf(wa.x, u[0], A[p]);
                A[p] = fmaf(wa.y, u[1], A[p]);
                A[p] = fmaf(wa.z, u[2], A[p]);
                A[p] = fmaf(wa.w, u[3], A[p]);
                P[p] = fmaf(wp.x, v[0], P[p]);
                P[p] = fmaf(wp.y, v[1], P[p]);
                P[p] = fmaf(wp.z, v[2], P[p]);
                P[p] = fmaf(wp.w, v[3], P[p]);
            }
        } else {
            #pragma unroll
            for (int p = 0; p < S_OUT; ++p) {
                const float* wa = wA_raw + (size_t)(cl * S_OUT + p) * S_IN + 4 * q;
                const float* wp = wP_raw + (size_t)(cl * S_OUT + p) * S_IN + 4 * q;
                #pragma unroll
                for (int j = 0; j < 4; ++j) {
                    A[p] = fmaf(wa[j], u[j], A[p]);
                    P[p] = fmaf(wp[j], v[j], P[p]);
                }
            }
        }

        // rotate pipeline registers
        if (q < NQ - 1) {
            #pragma unroll
            for (int j = 0; j < 4; ++j) {
                cxt[j] = nxt[j];
                cxr[j] = nxr[j];
            }
        }
    }

    // per-channel mean from pair u-sums
    if (pair < 7) {
        ssum[pair][cc] = (t == 0 || t == 6) ? 0.5f * su : su;
    }
    __syncthreads();
    float mean = 0.f;
    #pragma unroll
    for (int r = 0; r < 7; ++r) mean += ssum[r][cc];
    mean *= (1.0f / LL);

    if (!active) return;

    float* ob = out + ((size_t)b * PRED) * CC + c;

    #pragma unroll
    for (int p = 0; p < S_OUT; ++p) {
        float mc, bias_t, bias_r;
        if (TRANS) {
            mc     = mcoefT[p * CC + c];
            bias_t = biasv[(t  * S_OUT + p) * CC + c];
            bias_r = biasv[(tr * S_OUT + p) * CC + c];
        } else {
            float sw = 0.f;
            const float* wa = wA_raw + (size_t)(c * S_OUT + p) * S_IN;
            #pragma unroll
            for (int s = 0; s < S_IN; ++s) sw += wa[s];
            mc = 1.0f - sw;
            float ba = bAr[c * S_OUT + p], bp = bPr[c * S_OUT + p];
            bias_t = COEFP[t]  * bp + (t == 0 ? SQRT12F * ba : 0.f);
            bias_r = COEFP[tr] * bp;
        }
        const float mb = mean * mc;
        ob[(size_t)(p * WIN + t) * CC] = 0.5f * (A[p] + P[p]) + mb + bias_t;
        if (t != tr) {
            ob[(size_t)(p * WIN + tr) * CC] = 0.5f * (A[p] - P[p]) + mb + bias_r;
        }
    }
}

extern "C" void kernel_launch(void* const* d_in, const int* in_sizes, int n_in,
                              void* d_out, int out_size, void* d_ws, size_t ws_size,
                              hipStream_t stream) {
    const float* x  = (const float*)d_in[0];
    const float* wA = (const float*)d_in[1];
    const float* bA = (const float*)d_in[2];
    const float* wP = (const float*)d_in[3];
    const float* bP = (const float*)d_in[4];
    float* out = (float*)d_out;

    const size_t nW  = (size_t)NQ * S_OUT * CC * 4;  // 193088
    const size_t nM  = (size_t)S_OUT * CC;           // 6896
    const size_t nBv = (size_t)12 * S_OUT * CC;      // 82752
    const size_t need = (2 * nW + nM + nBv) * sizeof(float);

    dim3 grid(NTILES, BB);

    if (ws_size >= need) {
        float* wA4    = (float*)d_ws;
        float* wP4    = wA4 + nW;
        float* mcoefT = wP4 + nW;
        float* biasv  = mcoefT + nM;

        prep_w4<<<(int)((nW + 255) / 256), 256, 0, stream>>>(wA, wP, wA4, wP4);
        prep_mcoef<<<(int)((nM + 255) / 256), 256, 0, stream>>>(wA, mcoefT);
        prep_bias<<<(int)((nBv + 255) / 256), 256, 0, stream>>>(bA, bP, biasv);

        fused9<true><<<grid, 256, 0, stream>>>(
            x, wA4, wP4, mcoefT, biasv,
            nullptr, nullptr, nullptr, nullptr, out);
    } else {
        fused9<false><<<grid, 256, 0, stream>>>(
            x, nullptr, nullptr, nullptr, nullptr,
            wA, wP, bA, bP, out);
    }
}

// Round 10
// 85.701 us; speedup vs baseline: 1.6199x; 1.0432x over previous
//
#include <hip/hip_runtime.h>

#define BB 128
#define LL 336
#define CC 862
#define PRED 96
#define WIN 12
#define S_IN 28
#define S_OUT 8
#define CT 32
#define NTILES ((CC + CT - 1) / CT)   // 27

#define SQRT12F 3.4641016151377544f

// -Sb(t)/sqrt(12), Sb(t) = 2*sum_{k=1..5} sin(pi*k*t/6)   (exact closed forms)
__device__ const float COEFP[12] = {
    0.0f, -2.1547005383792515f, 0.0f, -0.5773502691896258f,
    0.0f, -0.15470053837925146f, 0.0f, 0.15470053837925146f,
    0.0f,  0.5773502691896258f, 0.0f,  2.1547005383792515f
};

// ---- prep kernels ----

// wXT layout: [p][s][c]  (c contiguous -> coalesced per-lane weight reads)
__global__ void prep_wT(const float* __restrict__ wA, const float* __restrict__ wP,
                        float* __restrict__ wAT, float* __restrict__ wPT) {
    int i = blockIdx.x * 256 + threadIdx.x;          // i = (p*S_IN + s)*CC + c
    if (i >= S_OUT * S_IN * CC) return;
    int c  = i % CC;
    int ps = i / CC;
    int s  = ps % S_IN;
    int p  = ps / S_IN;
    int src = (c * S_OUT + p) * S_IN + s;
    wAT[i] = wA[src];
    wPT[i] = wP[src];
}

__global__ void prep_mcoef(const float* __restrict__ wA, float* __restrict__ mcoefT) {
    int i = blockIdx.x * 256 + threadIdx.x;          // [p][c]
    if (i >= S_OUT * CC) return;
    int c = i % CC;
    int p = i / CC;
    float s = 0.f;
    for (int k = 0; k < S_IN; ++k) s += wA[(c * S_OUT + p) * S_IN + k];
    mcoefT[i] = 1.0f - s;
}

__global__ void prep_bias(const float* __restrict__ bA, const float* __restrict__ bP,
                          float* __restrict__ biasv) {
    int i = blockIdx.x * 256 + threadIdx.x;          // [t][p][c]
    if (i >= 12 * S_OUT * CC) return;
    int c = i % CC;
    int tp = i / CC;
    int p = tp % S_OUT;
    int t = tp / S_OUT;
    float v = COEFP[t] * bP[c * S_OUT + p];
    if (t == 0) v += SQRT12F * bA[c * S_OUT + p];
    biasv[i] = v;
}

// ---- fused main kernel: thread = (cc, p); x staged once in LDS (float2 fill);
//      s-loop unroll 4 (bounded VGPR); zero weight redundancy; mean free. ----
// r8 failed on VGPR=228 (full unroll, no cap) -> 11% occupancy.
// Fix: launch_bounds(256,4) + #pragma unroll 4.

template <bool TRANS>
__global__ __launch_bounds__(256, 4) void fused10(
    const float* __restrict__ x,
    const float* __restrict__ wAT, const float* __restrict__ wPT,
    const float* __restrict__ mcoefT, const float* __restrict__ biasv,
    const float* __restrict__ wA_raw, const float* __restrict__ wP_raw,
    const float* __restrict__ bAr, const float* __restrict__ bPr,
    float* __restrict__ out)
{
    __shared__ float sx[LL][CT];      // 43008 B

    const int b   = blockIdx.y;
    const int c0  = blockIdx.x * CT;
    const int NC  = min(CT, CC - c0); // 32 or 30 (always even)
    const int tid = threadIdx.x;

    // ---- stage x[b, :, c0:c0+NC]: 21 fully-unrolled independent float2 loads ----
    {
        const int j   = tid & 15;        // float2 slot in row
        const int r0  = tid >> 4;        // 0..15
        const int col = 2 * j;
        const int csrc = (col + 1 < NC) ? col : (NC - 2);   // NC even, >=2
        const float* base = x + ((size_t)b * LL) * CC + c0 + csrc;
        #pragma unroll
        for (int k = 0; k < 21; ++k) {
            const int r = r0 + k * 16;
            const float2 v = *reinterpret_cast<const float2*>(base + (size_t)r * CC);
            sx[r][col]     = v.x;
            sx[r][col + 1] = v.y;
        }
    }
    __syncthreads();

    const int cc = tid & 31;
    const int p  = tid >> 5;             // 0..7, all active
    const int c  = c0 + cc;
    const bool wr = (cc < NC);
    const int cl = wr ? c : (CC - 1);    // clamped for global weight loads

    float A0 = 0.f, A6 = 0.f;
    float Au[5] = {0.f, 0.f, 0.f, 0.f, 0.f};
    float Pv[5] = {0.f, 0.f, 0.f, 0.f, 0.f};
    float msum = 0.f;
    float sw = 0.f;                      // fallback: sum of wA over s

    #pragma unroll 4
    for (int s = 0; s < S_IN; ++s) {
        float wa, wp;
        if (TRANS) {
            wa = wAT[(size_t)(p * S_IN + s) * CC + cl];
            wp = wPT[(size_t)(p * S_IN + s) * CC + cl];
        } else {
            wa = wA_raw[(size_t)(cl * S_OUT + p) * S_IN + s];
            wp = wP_raw[(size_t)(cl * S_OUT + p) * S_IN + s];
            sw += wa;
        }
        float x12[12];
        #pragma unroll
        for (int t = 0; t < 12; ++t) x12[t] = sx[s * WIN + t][cc];

        A0 = fmaf(wa, x12[0], A0);
        A6 = fmaf(wa, x12[6], A6);
        float usum = x12[0] + x12[6];
        #pragma unroll
        for (int t = 1; t <= 5; ++t) {
            const float uu = x12[t] + x12[12 - t];
            const float vv = x12[t] - x12[12 - t];
            Au[t - 1] = fmaf(wa, uu, Au[t - 1]);
            Pv[t - 1] = fmaf(wp, vv, Pv[t - 1]);
            usum += uu;
        }
        msum += usum;
    }

    if (!wr) return;

    const float mean = msum * (1.0f / LL);

    float mc, bias[12];
    if (TRANS) {
        mc = mcoefT[p * CC + c];
        #pragma unroll
        for (int t = 0; t < 12; ++t) bias[t] = biasv[(size_t)(t * S_OUT + p) * CC + c];
    } else {
        mc = 1.0f - sw;
        const float ba = bAr[c * S_OUT + p], bp = bPr[c * S_OUT + p];
        #pragma unroll
        for (int t = 0; t < 12; ++t) {
            bias[t] = COEFP[t] * bp + (t == 0 ? SQRT12F * ba : 0.f);
        }
    }

    const float mb = mean * mc;
    float* ob = out + ((size_t)b * PRED + p * WIN) * CC + c;

    ob[0]               = A0 + mb + bias[0];
    ob[(size_t)6 * CC]  = A6 + mb + bias[6];
    #pragma unroll
    for (int t = 1; t <= 5; ++t) {
        ob[(size_t)t * CC]        = 0.5f * (Au[t-1] + Pv[t-1]) + mb + bias[t];
        ob[(size_t)(12 - t) * CC] = 0.5f * (Au[t-1] - Pv[t-1]) + mb + bias[12 - t];
    }
}

extern "C" void kernel_launch(void* const* d_in, const int* in_sizes, int n_in,
                              void* d_out, int out_size, void* d_ws, size_t ws_size,
                              hipStream_t stream) {
    const float* x  = (const float*)d_in[0];
    const float* wA = (const float*)d_in[1];
    const float* bA = (const float*)d_in[2];
    const float* wP = (const float*)d_in[3];
    const float* bP = (const float*)d_in[4];
    float* out = (float*)d_out;

    const size_t nW  = (size_t)S_OUT * S_IN * CC;    // 193088
    const size_t nM  = (size_t)S_OUT * CC;           // 6896
    const size_t nBv = (size_t)12 * S_OUT * CC;      // 82752
    const size_t need = (2 * nW + nM + nBv) * sizeof(float);

    dim3 grid(NTILES, BB);

    if (ws_size >= need) {
        float* wAT    = (float*)d_ws;
        float* wPT    = wAT + nW;
        float* mcoefT = wPT + nW;
        float* biasv  = mcoefT + nM;

        prep_wT<<<(int)((nW + 255) / 256), 256, 0, stream>>>(wA, wP, wAT, wPT);
        prep_mcoef<<<(int)((nM + 255) / 256), 256, 0, stream>>>(wA, mcoefT);
        prep_bias<<<(int)((nBv + 255) / 256), 256, 0, stream>>>(bA, bP, biasv);

        fused10<true><<<grid, 256, 0, stream>>>(
            x, wAT, wPT, mcoefT, biasv,
            nullptr, nullptr, nullptr, nullptr, out);
    } else {
        fused10<false><<<grid, 256, 0, stream>>>(
            x, nullptr, nullptr, nullptr, nullptr,
            wA, wP, bA, bP, out);
    }
}